// Round 2
// baseline (2368.953 us; speedup 1.0000x reference)
//
#include <hip/hip_runtime.h>
#include <hip/hip_bf16.h>
#include <stdint.h>

#define BB 8
#define NN 256
#define HH 512
#define G4 2048       // 4*HH
#define EE 512
#define RDIM 64
#define KX 576        // RDIM + EE
#define VV 32000

using f32x4 = __attribute__((ext_vector_type(4))) float;
using bf16x8 = __attribute__((ext_vector_type(8))) short;

__device__ __forceinline__ unsigned short f2bf(float f) {
  unsigned int u = __float_as_uint(f);
  u = (u + 0x7FFFu + ((u >> 16) & 1u)) >> 16;
  return (unsigned short)u;
}
__device__ __forceinline__ float sigm(float x) { return 1.0f / (1.0f + __expf(-x)); }

// ---------------- init: Hs[0]=root_h, Cs[0]=root_h (ref: Cs0 = Hs0), ready[0]=1
__global__ void init_kernel(const float* __restrict__ root_h, float* __restrict__ Hs,
                            float* __restrict__ Cs, int* __restrict__ ready) {
  int i = blockIdx.x * 256 + threadIdx.x;   // 0..4095
  float v = root_h[i];
  Hs[i] = v;
  Cs[i] = v;
  if (i == 0) ready[0] = 1;
}

// ---------------- Xg = concat(rel_emb[rel], word_emb[pword]) @ Wx + b
// grid (8 colblocks, 256 nodes), 256 threads. Xg layout [n][b][2048]
__global__ __launch_bounds__(256) void xg_kernel(
    const int* __restrict__ rel_ids, const int* __restrict__ sent_ids,
    const int* __restrict__ parent, const float* __restrict__ word_emb,
    const float* __restrict__ rel_emb, const float* __restrict__ Wx,
    const float* __restrict__ bias, float* __restrict__ Xg) {
  int n = blockIdx.y;
  int cb = blockIdx.x;
  int tid = threadIdx.x;
  __shared__ float xs[BB * KX];     // [b][k], k contiguous
  int par = parent[n];
  int b = tid >> 5;
  int l32 = tid & 31;
  int rid = rel_ids[b * NN + n];
  int pw = (par < 0) ? 0 : sent_ids[b * NN + par];   // SOS = 0
  const float* re = rel_emb + (size_t)rid * RDIM;
  const float* we = word_emb + (size_t)pw * EE;
  for (int q = l32; q < RDIM; q += 32) xs[b * KX + q] = re[q];
  for (int q = l32; q < EE; q += 32) xs[b * KX + RDIM + q] = we[q];
  __syncthreads();
  int col = cb * 256 + tid;
  float bb = bias[col];
  float acc[BB];
#pragma unroll
  for (int i = 0; i < BB; ++i) acc[i] = bb;
  const float* wxp = Wx + col;
  for (int k = 0; k < KX; k += 4) {
    float w0 = wxp[(size_t)(k + 0) * G4];
    float w1 = wxp[(size_t)(k + 1) * G4];
    float w2 = wxp[(size_t)(k + 2) * G4];
    float w3 = wxp[(size_t)(k + 3) * G4];
#pragma unroll
    for (int i = 0; i < BB; ++i) {
      f32x4 p = *(const f32x4*)&xs[i * KX + k];  // uniform broadcast
      acc[i] = fmaf(p[0], w0, acc[i]);
      acc[i] = fmaf(p[1], w1, acc[i]);
      acc[i] = fmaf(p[2], w2, acc[i]);
      acc[i] = fmaf(p[3], w3, acc[i]);
    }
  }
  float* xgout = Xg + (size_t)n * (BB * G4) + col;
#pragma unroll
  for (int i = 0; i < BB; ++i) xgout[(size_t)i * G4] = acc[i];
}

// ---------------- Wo (512 x 32000) f32  ->  WoT (32000 x 512) bf16
// grid (500 n-tiles, 8 k-tiles), 256 threads, 64x64 tile
__global__ __launch_bounds__(256) void wot_kernel(const float* __restrict__ Wo,
                                                  unsigned short* __restrict__ WoT) {
  __shared__ float t[64][65];
  int n0 = blockIdx.x * 64;
  int k0 = blockIdx.y * 64;
  int tid = threadIdx.x;
  int c = tid & 63;
  int r4 = tid >> 6;
#pragma unroll
  for (int i = 0; i < 16; ++i) {
    int r = r4 * 16 + i;                       // local k
    t[r][c] = Wo[(size_t)(k0 + r) * VV + n0 + c];
  }
  __syncthreads();
#pragma unroll
  for (int i = 0; i < 16; ++i) {
    int nr = r4 * 16 + i;                      // local n
    WoT[(size_t)(n0 + nr) * HH + k0 + c] = f2bf(t[c][nr]);
  }
}

// ---------------- dataflow tree-LSTM scan (COOPERATIVE launch: co-residency
// guaranteed, spin is deadlock-free since node waits only on lower-index node)
// 512 blocks x 256 threads. group = bid&63 handles nodes g, g+64, ...; w = bid>>6
// selects 64-hidden slice. Per node: g = Xg + ph@Wh; LSTM cell; signal ready.
__global__ __launch_bounds__(256, 2) void scan_kernel(
    const int* __restrict__ parent, const float* __restrict__ Wh,
    const float* __restrict__ Xg, float* __restrict__ Hs, float* __restrict__ Cs,
    unsigned short* __restrict__ hs_bf, int* ready, int* done) {
  int g = blockIdx.x & 63;
  int w = blockIdx.x >> 6;          // 0..7
  int tid = threadIdx.x;
  int gate = tid >> 6;              // 0..3
  int kk = tid & 63;
  int k0 = w * 64;
  __shared__ float ph[BB * HH];     // parent h, [b][j]  (16 KB)
  __shared__ float glds[BB * 256];  // gates [b][gate][kk] (8 KB)
  for (int node = g; node < NN; node += 64) {
    int slot = parent[node] + 1;
    if (tid == 0) {
      // bounded spin watchdog: never hang the container; a timeout shows up
      // as an absmax failure instead.
      for (long spin = 0; spin < 50000000L; ++spin) {
        if (__hip_atomic_load(&ready[slot], __ATOMIC_ACQUIRE,
                              __HIP_MEMORY_SCOPE_AGENT) != 0) break;
        __builtin_amdgcn_s_sleep(1);
      }
    }
    __syncthreads();
    // stage parent h into LDS (4096 floats)
    const f32x4* src = (const f32x4*)(Hs + (size_t)slot * (BB * HH));
    f32x4* dst = (f32x4*)ph;
    for (int t = tid; t < (BB * HH / 4); t += 256) dst[t] = src[t];
    __syncthreads();

    int col = gate * HH + k0 + kk;
    const float* xgp = Xg + (size_t)node * (BB * G4) + col;
    float acc[BB];
#pragma unroll
    for (int i = 0; i < BB; ++i) acc[i] = xgp[(size_t)i * G4];
    const float* whp = Wh + col;
    for (int j = 0; j < HH; j += 4) {
      float w0 = whp[(size_t)(j + 0) * G4];
      float w1 = whp[(size_t)(j + 1) * G4];
      float w2 = whp[(size_t)(j + 2) * G4];
      float w3 = whp[(size_t)(j + 3) * G4];
#pragma unroll
      for (int i = 0; i < BB; ++i) {
        f32x4 p = *(const f32x4*)&ph[i * HH + j];  // uniform broadcast b128
        acc[i] = fmaf(p[0], w0, acc[i]);
        acc[i] = fmaf(p[1], w1, acc[i]);
        acc[i] = fmaf(p[2], w2, acc[i]);
        acc[i] = fmaf(p[3], w3, acc[i]);
      }
    }
#pragma unroll
    for (int i = 0; i < BB; ++i) glds[i * 256 + gate * 64 + kk] = acc[i];
    __syncthreads();
    // combine gates -> c, h for 512 (b, hidden) pairs
    for (int t = tid; t < BB * 64; t += 256) {
      int b = t >> 6;
      int kx = t & 63;
      int hidx = k0 + kx;
      float ig = glds[b * 256 + 0 * 64 + kx];
      float fg = glds[b * 256 + 1 * 64 + kx];
      float og = glds[b * 256 + 2 * 64 + kx];
      float gg = glds[b * 256 + 3 * 64 + kx];
      float pc = Cs[(size_t)slot * (BB * HH) + b * HH + hidx];
      float c = sigm(fg) * pc + sigm(ig) * tanhf(gg);
      float h = sigm(og) * tanhf(c);
      size_t oi = (size_t)(node + 1) * (BB * HH) + b * HH + hidx;
      Cs[oi] = c;
      Hs[oi] = h;
      hs_bf[(size_t)(b * NN + node) * HH + hidx] = f2bf(h);
    }
    __threadfence();
    __syncthreads();
    if (tid == 0) {
      int prev = __hip_atomic_fetch_add(&done[node], 1, __ATOMIC_ACQ_REL,
                                        __HIP_MEMORY_SCOPE_AGENT);
      if (prev == 7) {
        __hip_atomic_store(&ready[node + 1], 1, __ATOMIC_RELEASE,
                           __HIP_MEMORY_SCOPE_AGENT);
      }
    }
  }
}

// ---------------- logits = hs_bf (2048x512) @ WoT^T (32000x512) + bo, f32 out
// 128x128 tile, BK=32, 4 waves (2x2 of 64x64), 16x16x32 bf16 MFMA
__global__ __launch_bounds__(256) void gemm_kernel(
    const unsigned short* __restrict__ A, const unsigned short* __restrict__ Bt,
    const float* __restrict__ bo, float* __restrict__ C) {
  int bid = blockIdx.x;                    // 0..3999
  int swz = (bid & 7) * 500 + (bid >> 3);  // XCD-contiguous chunks
  int nt = swz >> 4;                       // 0..249  (m fastest within chunk)
  int mt = swz & 15;                       // 0..15
  int tid = threadIdx.x;
  int wave = tid >> 6;
  int lane = tid & 63;
  int wr = wave >> 1, wc = wave & 1;
  int lr = lane & 15, lh = lane >> 4;
  __shared__ __align__(16) unsigned short Al[128 * 32];
  __shared__ __align__(16) unsigned short Bl[128 * 32];
  int m0 = mt * 128, n0 = nt * 128;
  f32x4 acc[4][4];
#pragma unroll
  for (int i = 0; i < 4; ++i)
#pragma unroll
    for (int j = 0; j < 4; ++j) acc[i][j] = (f32x4){0.f, 0.f, 0.f, 0.f};

  for (int k0 = 0; k0 < HH; k0 += 32) {
#pragma unroll
    for (int q = 0; q < 2; ++q) {
      int off = wave * 2048 + q * 1024 + lane * 16;  // byte offset in tile
      int r = off >> 6;                              // tile row (64 B/row)
      int cb = off & 63;                             // byte within row
      const unsigned short* ga = A + (size_t)(m0 + r) * HH + k0 + (cb >> 1);
      const unsigned short* gb = Bt + (size_t)(n0 + r) * HH + k0 + (cb >> 1);
      __builtin_amdgcn_global_load_lds(
          (const __attribute__((address_space(1))) unsigned int*)ga,
          (__attribute__((address_space(3))) unsigned int*)((char*)Al + wave * 2048 + q * 1024),
          16, 0, 0);
      __builtin_amdgcn_global_load_lds(
          (const __attribute__((address_space(1))) unsigned int*)gb,
          (__attribute__((address_space(3))) unsigned int*)((char*)Bl + wave * 2048 + q * 1024),
          16, 0, 0);
    }
    __syncthreads();
    bf16x8 af[4], bfr[4];
#pragma unroll
    for (int i = 0; i < 4; ++i) {
      af[i] = *(const bf16x8*)&Al[(wr * 64 + i * 16 + lr) * 32 + lh * 8];
      bfr[i] = *(const bf16x8*)&Bl[(wc * 64 + i * 16 + lr) * 32 + lh * 8];
    }
#pragma unroll
    for (int i = 0; i < 4; ++i)
#pragma unroll
      for (int j = 0; j < 4; ++j)
        acc[i][j] = __builtin_amdgcn_mfma_f32_16x16x32_bf16(af[i], bfr[j], acc[i][j], 0, 0, 0);
    __syncthreads();
  }
#pragma unroll
  for (int j = 0; j < 4; ++j) {
    int v = n0 + wc * 64 + j * 16 + lr;
    float bias = bo[v];
#pragma unroll
    for (int i = 0; i < 4; ++i) {
#pragma unroll
      for (int r2 = 0; r2 < 4; ++r2) {
        int m = m0 + wr * 64 + i * 16 + lh * 4 + r2;
        C[(size_t)m * VV + v] = acc[i][j][r2] + bias;
      }
    }
  }
}

// ---------------- workspace layout (bytes)
static const size_t OFF_READY = 0;                       // int[257]
static const size_t OFF_DONE = 2048;                     // int[256]
static const size_t OFF_HS = 8192;                       // 257*8*512*4 = 4210688
static const size_t OFF_CS = OFF_HS + 4210688;           // 4218880
static const size_t OFF_XG = OFF_CS + 4210688;           // 8429568, 16777216 B
static const size_t OFF_HSBF = OFF_XG + 16777216;        // 25206784, 2097152 B
static const size_t OFF_WOT = OFF_HSBF + 2097152;        // 27303936, 32768000 B
// total = 60,071,936 bytes

extern "C" void kernel_launch(void* const* d_in, const int* in_sizes, int n_in,
                              void* d_out, int out_size, void* d_ws, size_t ws_size,
                              hipStream_t stream) {
  const int* rel_ids = (const int*)d_in[0];
  const int* sent_ids = (const int*)d_in[1];
  const int* parent = (const int*)d_in[2];
  const float* root_h = (const float*)d_in[3];
  const float* word_emb = (const float*)d_in[4];
  const float* rel_emb = (const float*)d_in[5];
  const float* Wx = (const float*)d_in[6];
  const float* Wh = (const float*)d_in[7];
  const float* bias = (const float*)d_in[8];
  const float* Wo = (const float*)d_in[9];
  const float* bo = (const float*)d_in[10];
  float* out = (float*)d_out;

  char* ws = (char*)d_ws;
  int* ready = (int*)(ws + OFF_READY);
  int* done = (int*)(ws + OFF_DONE);
  float* Hs = (float*)(ws + OFF_HS);
  float* Cs = (float*)(ws + OFF_CS);
  float* Xg = (float*)(ws + OFF_XG);
  unsigned short* hs_bf = (unsigned short*)(ws + OFF_HSBF);
  unsigned short* WoT = (unsigned short*)(ws + OFF_WOT);

  hipMemsetAsync(ws, 0, 8192, stream);  // flags
  init_kernel<<<16, 256, 0, stream>>>(root_h, Hs, Cs, ready);
  xg_kernel<<<dim3(8, 256), 256, 0, stream>>>(rel_ids, sent_ids, parent, word_emb,
                                              rel_emb, Wx, bias, Xg);
  wot_kernel<<<dim3(500, 8), 256, 0, stream>>>(Wo, WoT);
  {
    void* args[] = {(void*)&parent, (void*)&Wh, (void*)&Xg, (void*)&Hs,
                    (void*)&Cs, (void*)&hs_bf, (void*)&ready, (void*)&done};
    hipLaunchCooperativeKernel((void*)scan_kernel, dim3(512), dim3(256), args, 0,
                               stream);
  }
  gemm_kernel<<<4000, 256, 0, stream>>>(hs_bf, WoT, bo, out);
}